// Round 1
// baseline (1339.151 us; speedup 1.0000x reference)
//
#include <hip/hip_runtime.h>
#include <hip/hip_bf16.h>

#define NTOK 16384
#define CDIM 768
#define FDIM 3072
#define NEXP 8
#define NSLOT 32768   // NTOK * TOPK

typedef __attribute__((ext_vector_type(8))) short bf16x8;
typedef __attribute__((ext_vector_type(4))) float f32x4;

__device__ __forceinline__ unsigned short f2bf(float f) {
  unsigned int u = __float_as_uint(f);
  u += 0x7FFFu + ((u >> 16) & 1u);   // RNE
  return (unsigned short)(u >> 16);
}

__device__ __forceinline__ void async16(const void* g, void* l) {
  __builtin_amdgcn_global_load_lds(
      (const __attribute__((address_space(1))) unsigned int*)g,
      (__attribute__((address_space(3))) unsigned int*)l, 16, 0, 0);
}

// ---------------- transpose + fp32->bf16 convert ----------------
// src: [E][R][Cc] fp32  ->  dst: [E][Cc][R] bf16
__global__ __launch_bounds__(256)
void k_transpose(const float* __restrict__ src, unsigned short* __restrict__ dst,
                 int R, int Cc)
{
  __shared__ float tle[32][33];
  int e = blockIdx.z;
  int c0 = blockIdx.x * 32, r0 = blockIdx.y * 32;
  int tx = threadIdx.x & 31, ty = threadIdx.x >> 5;
  const float* s = src + (size_t)e * R * Cc;
  unsigned short* d = dst + (size_t)e * R * Cc;
#pragma unroll
  for (int i = 0; i < 4; ++i)
    tle[ty + i * 8][tx] = s[(size_t)(r0 + ty + i * 8) * Cc + c0 + tx];
  __syncthreads();
#pragma unroll
  for (int i = 0; i < 4; ++i)
    d[(size_t)(c0 + ty + i * 8) * R + r0 + tx] = f2bf(tle[tx][ty + i * 8]);
}

// ---------------- router: fp32 logits, top-2, weights ----------------
__global__ __launch_bounds__(256)
void k_router(const float* __restrict__ x, const float* __restrict__ rw,
              int* __restrict__ counts, int* __restrict__ tk_e,
              float* __restrict__ tk_w, int* __restrict__ tk_idx)
{
  __shared__ float srw[NEXP * CDIM];
  int tid = threadIdx.x;
#pragma unroll
  for (int i = 0; i < (NEXP * CDIM / 4) / 256; ++i)
    ((float4*)srw)[tid + i * 256] = ((const float4*)rw)[tid + i * 256];
  __syncthreads();
  int lane = tid & 63, wid = tid >> 6;
  int t = blockIdx.x * 4 + wid;
  float a[NEXP];
#pragma unroll
  for (int e = 0; e < NEXP; ++e) a[e] = 0.f;
  const float* xr = x + (size_t)t * CDIM;
#pragma unroll
  for (int c = 0; c < CDIM / 64; ++c) {
    float xv = xr[c * 64 + lane];
#pragma unroll
    for (int e = 0; e < NEXP; ++e) a[e] += xv * srw[e * CDIM + c * 64 + lane];
  }
#pragma unroll
  for (int e = 0; e < NEXP; ++e) {
#pragma unroll
    for (int off = 32; off; off >>= 1) a[e] += __shfl_xor(a[e], off);
  }
  if (lane == 0) {
    int i0 = 0; float l0 = a[0];
#pragma unroll
    for (int e = 1; e < NEXP; ++e) if (a[e] > l0) { l0 = a[e]; i0 = e; }
    int i1 = -1; float l1 = -1e30f;
#pragma unroll
    for (int e = 0; e < NEXP; ++e) if (e != i0 && a[e] > l1) { l1 = a[e]; i1 = e; }
    // softmax-then-renormalize over top2 == 2-way softmax of logits
    float w0 = 1.f / (1.f + expf(l1 - l0));
    float w1v = 1.f - w0;
    int idx0 = atomicAdd(&counts[i0], 1);
    int idx1 = atomicAdd(&counts[i1], 1);
    tk_e[2 * t] = i0;   tk_e[2 * t + 1] = i1;
    tk_w[2 * t] = w0;   tk_w[2 * t + 1] = w1v;
    tk_idx[2 * t] = idx0; tk_idx[2 * t + 1] = idx1;
  }
}

// ---------------- scan: expert offsets + 128-row tile prefix ----------------
__global__ void k_scan(const int* __restrict__ counts, int* __restrict__ offsets,
                       int* __restrict__ tp)
{
  offsets[0] = 0; tp[0] = 0;
  for (int e = 0; e < NEXP; ++e) {
    offsets[e + 1] = offsets[e] + counts[e];
    tp[e + 1] = tp[e] + (counts[e] + 127) / 128;
  }
}

// ---------------- gather x rows into expert-grouped bf16 Xg ----------------
__global__ __launch_bounds__(64)
void k_gather(const float* __restrict__ x, const int* __restrict__ tk_e,
              const float* __restrict__ tk_w, const int* __restrict__ tk_idx,
              const int* __restrict__ offsets, int* __restrict__ slot_token,
              float* __restrict__ slot_w, unsigned short* __restrict__ Xg)
{
  int b = blockIdx.x;
  int t = b >> 1, kk = b & 1;
  int e = tk_e[2 * t + kk];
  int slot = offsets[e] + tk_idx[2 * t + kk];
  if (threadIdx.x == 0) { slot_token[slot] = t; slot_w[slot] = tk_w[2 * t + kk]; }
  const float4* src = (const float4*)(x + (size_t)t * CDIM);
  ushort4* dst = (ushort4*)(Xg + (size_t)slot * CDIM);
#pragma unroll
  for (int i = 0; i < 3; ++i) {
    float4 v = src[i * 64 + threadIdx.x];
    ushort4 h;
    h.x = f2bf(v.x); h.y = f2bf(v.y); h.z = f2bf(v.z); h.w = f2bf(v.w);
    dst[i * 64 + threadIdx.x] = h;
  }
}

// ---------------- grouped GEMM, 128x128 tile, BK=32, 4 waves ----------------
// A: [rows][lda] bf16 (expert-grouped rows). B: per-expert [n][ldb] bf16 (k-contig rows).
// EPI==0: H[rowbase+row][ncol] = bf16(gelu(acc + b1[e][n0base+ncol]))
// EPI==1: atomicAdd(out[token][ncol], (acc + b2[e][ncol]) * slot_w[row])
template <int EPI>
__global__ __launch_bounds__(256)
void k_gemm(const unsigned short* __restrict__ A, int lda,
            const unsigned short* __restrict__ B, int ldb, long sB, int bkoff,
            int Ksteps,
            const int* __restrict__ counts, const int* __restrict__ offsets,
            const int* __restrict__ tp,
            int n0base, const float* __restrict__ bias, int biasStride,
            unsigned short* __restrict__ Hout, int ldh,
            float* __restrict__ Out,
            const int* __restrict__ slot_token, const float* __restrict__ slot_w)
{
  __shared__ __align__(16) unsigned short smA[128 * 32];
  __shared__ __align__(16) unsigned short smB[128 * 32];

  int by = blockIdx.y;
  if (by >= tp[NEXP]) return;
  int e = 0;
  while (by >= tp[e + 1]) ++e;
  int rowtile = by - tp[e];
  int m0 = rowtile * 128;
  int cnt = counts[e];
  int rowbase = offsets[e];

  int n0 = blockIdx.x * 128;
  const unsigned short* Bexp = B + (long)e * sB + bkoff + (long)(n0base + n0) * ldb;
  const unsigned short* Aexp = A + (long)(rowbase + m0) * lda;

  int tid = threadIdx.x;
  int lane = tid & 63, wid = tid >> 6;
  int wm = wid >> 1, wn = wid & 1;

  f32x4 acc[4][4] = {};

  // staging map: thread covers LDS bytes [tid*16,+16) and [4096+tid*16,+16)
  int lin0 = tid * 16;
  int rA0 = lin0 >> 6;             // 64 bytes per 32-elem bf16 row
  int kA0 = (lin0 & 63) >> 1;      // bf16 element within row
  char* smAb = (char*)smA;
  char* smBb = (char*)smB;
  char* ldsA0 = smAb + wid * 1024;
  char* ldsA1 = smAb + 4096 + wid * 1024;
  char* ldsB0 = smBb + wid * 1024;
  char* ldsB1 = smBb + 4096 + wid * 1024;

  int ar = lane & 15, kg = lane >> 4;

  for (int ks = 0; ks < Ksteps; ++ks) {
    int k0 = ks * 32;
    async16(Aexp + (long)rA0 * lda + k0 + kA0, ldsA0);
    async16(Aexp + (long)(rA0 + 64) * lda + k0 + kA0, ldsA1);
    async16(Bexp + (long)rA0 * ldb + k0 + kA0, ldsB0);
    async16(Bexp + (long)(rA0 + 64) * ldb + k0 + kA0, ldsB1);
    __syncthreads();
    bf16x8 af[4], bfr[4];
#pragma unroll
    for (int i = 0; i < 4; ++i)
      af[i] = *(const bf16x8*)(smA + ((wm * 64 + i * 16 + ar) * 32 + kg * 8));
#pragma unroll
    for (int i = 0; i < 4; ++i)
      bfr[i] = *(const bf16x8*)(smB + ((wn * 64 + i * 16 + ar) * 32 + kg * 8));
#pragma unroll
    for (int mi = 0; mi < 4; ++mi)
#pragma unroll
      for (int ni = 0; ni < 4; ++ni)
        acc[mi][ni] = __builtin_amdgcn_mfma_f32_16x16x32_bf16(af[mi], bfr[ni],
                                                              acc[mi][ni], 0, 0, 0);
    __syncthreads();
  }

  if (EPI == 0) {
#pragma unroll
    for (int ni = 0; ni < 4; ++ni) {
      int ncol = n0 + wn * 64 + ni * 16 + ar;
      float bv = bias[e * biasStride + n0base + ncol];
#pragma unroll
      for (int mi = 0; mi < 4; ++mi) {
#pragma unroll
        for (int r = 0; r < 4; ++r) {
          int row = m0 + wm * 64 + mi * 16 + kg * 4 + r;
          if (row < cnt) {
            float v = acc[mi][ni][r] + bv;
            v = 0.5f * v * (1.0f + erff(v * 0.70710678118654752f));
            Hout[(long)(rowbase + row) * ldh + ncol] = f2bf(v);
          }
        }
      }
    }
  } else {
#pragma unroll
    for (int mi = 0; mi < 4; ++mi) {
#pragma unroll
      for (int r = 0; r < 4; ++r) {
        int row = m0 + wm * 64 + mi * 16 + kg * 4 + r;
        if (row < cnt) {
          int token = slot_token[rowbase + row];
          float wt = slot_w[rowbase + row];
#pragma unroll
          for (int ni = 0; ni < 4; ++ni) {
            int ncol = n0 + wn * 64 + ni * 16 + ar;
            float v = (acc[mi][ni][r] + bias[e * biasStride + ncol]) * wt;
            atomicAdd(&Out[(long)token * CDIM + ncol], v);
          }
        }
      }
    }
  }
}

extern "C" void kernel_launch(void* const* d_in, const int* in_sizes, int n_in,
                              void* d_out, int out_size, void* d_ws, size_t ws_size,
                              hipStream_t stream) {
  const float* x        = (const float*)d_in[0];
  const float* router_w = (const float*)d_in[1];
  const float* w1       = (const float*)d_in[2];
  const float* b1       = (const float*)d_in[3];
  const float* w2       = (const float*)d_in[4];
  const float* b2       = (const float*)d_in[5];
  float* out = (float*)d_out;

  char* ws = (char*)d_ws;
  size_t off = 0;
  auto alloc = [&](size_t bytes) -> void* {
    void* p = ws + off;
    off = (off + bytes + 255) & ~(size_t)255;
    return p;
  };
  int*   counts     = (int*)alloc(NEXP * 4);
  int*   offsets    = (int*)alloc((NEXP + 1) * 4);
  int*   tp         = (int*)alloc((NEXP + 1) * 4);
  int*   tk_e       = (int*)alloc((size_t)NTOK * 2 * 4);
  float* tk_w       = (float*)alloc((size_t)NTOK * 2 * 4);
  int*   tk_idx     = (int*)alloc((size_t)NTOK * 2 * 4);
  int*   slot_token = (int*)alloc((size_t)NSLOT * 4);
  float* slot_w     = (float*)alloc((size_t)NSLOT * 4);
  unsigned short* w1t = (unsigned short*)alloc((size_t)NEXP * FDIM * CDIM * 2);
  unsigned short* w2t = (unsigned short*)alloc((size_t)NEXP * CDIM * FDIM * 2);
  unsigned short* Xg  = (unsigned short*)alloc((size_t)(NSLOT + 128) * CDIM * 2);
  // H chunked over F if ws is tight
  int FC = FDIM;
  while (FC > 768 && off + (size_t)(NSLOT + 128) * FC * 2 > ws_size) FC >>= 1;
  unsigned short* H = (unsigned short*)alloc((size_t)(NSLOT + 128) * FC * 2);

  hipMemsetAsync(out, 0, (size_t)NTOK * CDIM * 4, stream);
  hipMemsetAsync(counts, 0, NEXP * 4, stream);

  k_transpose<<<dim3(FDIM / 32, CDIM / 32, NEXP), 256, 0, stream>>>(w1, w1t, CDIM, FDIM);
  k_transpose<<<dim3(CDIM / 32, FDIM / 32, NEXP), 256, 0, stream>>>(w2, w2t, FDIM, CDIM);
  k_router<<<NTOK / 4, 256, 0, stream>>>(x, router_w, counts, tk_e, tk_w, tk_idx);
  k_scan<<<1, 1, 0, stream>>>(counts, offsets, tp);
  k_gather<<<NSLOT, 64, 0, stream>>>(x, tk_e, tk_w, tk_idx, offsets,
                                     slot_token, slot_w, Xg);

  const int MAXTILES = NSLOT / 128 + NEXP - 1;  // 263
  for (int f0 = 0; f0 < FDIM; f0 += FC) {
    k_gemm<0><<<dim3(FC / 128, MAXTILES), 256, 0, stream>>>(
        Xg, CDIM, w1t, CDIM, (long)FDIM * CDIM, 0, CDIM / 32,
        counts, offsets, tp, f0, b1, FDIM, H, FC, nullptr, nullptr, nullptr);
    k_gemm<1><<<dim3(CDIM / 128, MAXTILES), 256, 0, stream>>>(
        H, FC, w2t, FDIM, (long)CDIM * FDIM, f0, FC / 32,
        counts, offsets, tp, 0, b2, CDIM, nullptr, 0, out, slot_token, slot_w);
  }
}

// Round 2
// 981.372 us; speedup vs baseline: 1.3646x; 1.3646x over previous
//
#include <hip/hip_runtime.h>
#include <hip/hip_bf16.h>

#define NTOK 16384
#define CDIM 768
#define FDIM 3072
#define NEXP 8
#define NSLOT 32768   // NTOK * TOPK
#define HBLK 128      // histogram blocks (NSLOT / 256)

typedef __attribute__((ext_vector_type(8))) short bf16x8;
typedef __attribute__((ext_vector_type(4))) float f32x4;

__device__ __forceinline__ unsigned short f2bf(float f) {
  unsigned int u = __float_as_uint(f);
  u += 0x7FFFu + ((u >> 16) & 1u);   // RNE
  return (unsigned short)(u >> 16);
}

__device__ __forceinline__ void async16(const void* g, void* l) {
  __builtin_amdgcn_global_load_lds(
      (const __attribute__((address_space(1))) unsigned int*)g,
      (__attribute__((address_space(3))) unsigned int*)l, 16, 0, 0);
}

// ---------------- transpose + fp32->bf16 convert ----------------
// src: [E][R][Cc] fp32  ->  dst: [E][Cc][R] bf16
__global__ __launch_bounds__(256)
void k_transpose(const float* __restrict__ src, unsigned short* __restrict__ dst,
                 int R, int Cc)
{
  __shared__ float tle[32][33];
  int e = blockIdx.z;
  int c0 = blockIdx.x * 32, r0 = blockIdx.y * 32;
  int tx = threadIdx.x & 31, ty = threadIdx.x >> 5;
  const float* s = src + (size_t)e * R * Cc;
  unsigned short* d = dst + (size_t)e * R * Cc;
#pragma unroll
  for (int i = 0; i < 4; ++i)
    tle[ty + i * 8][tx] = s[(size_t)(r0 + ty + i * 8) * Cc + c0 + tx];
  __syncthreads();
#pragma unroll
  for (int i = 0; i < 4; ++i)
    d[(size_t)(c0 + ty + i * 8) * R + r0 + tx] = f2bf(tle[tx][ty + i * 8]);
}

// ---------------- router: fp32 logits, top-2, weights (NO atomics) -----------
__global__ __launch_bounds__(256)
void k_router(const float* __restrict__ x, const float* __restrict__ rw,
              int* __restrict__ tk_e, float* __restrict__ tk_w)
{
  __shared__ float srw[NEXP * CDIM];
  int tid = threadIdx.x;
#pragma unroll
  for (int i = 0; i < (NEXP * CDIM / 4) / 256; ++i)
    ((float4*)srw)[tid + i * 256] = ((const float4*)rw)[tid + i * 256];
  __syncthreads();
  int lane = tid & 63, wid = tid >> 6;
  int t = blockIdx.x * 4 + wid;
  float a[NEXP];
#pragma unroll
  for (int e = 0; e < NEXP; ++e) a[e] = 0.f;
  const float* xr = x + (size_t)t * CDIM;
#pragma unroll
  for (int c = 0; c < CDIM / 64; ++c) {
    float xv = xr[c * 64 + lane];
#pragma unroll
    for (int e = 0; e < NEXP; ++e) a[e] += xv * srw[e * CDIM + c * 64 + lane];
  }
#pragma unroll
  for (int e = 0; e < NEXP; ++e) {
#pragma unroll
    for (int off = 32; off; off >>= 1) a[e] += __shfl_xor(a[e], off);
  }
  if (lane == 0) {
    int i0 = 0; float l0 = a[0];
#pragma unroll
    for (int e = 1; e < NEXP; ++e) if (a[e] > l0) { l0 = a[e]; i0 = e; }
    int i1 = -1; float l1 = -1e30f;
#pragma unroll
    for (int e = 0; e < NEXP; ++e) if (e != i0 && a[e] > l1) { l1 = a[e]; i1 = e; }
    float w0 = 1.f / (1.f + expf(l1 - l0));   // top2 softmax-renorm
    tk_e[2 * t] = i0;     tk_e[2 * t + 1] = i1;
    tk_w[2 * t] = w0;     tk_w[2 * t + 1] = 1.f - w0;
  }
}

// ---------------- per-block expert histogram ----------------
__global__ __launch_bounds__(256)
void k_hist(const int* __restrict__ tk_e, int* __restrict__ blockhist)
{
  __shared__ int h[NEXP];
  int tid = threadIdx.x;
  if (tid < NEXP) h[tid] = 0;
  __syncthreads();
  int e = tk_e[blockIdx.x * 256 + tid];
  atomicAdd(&h[e], 1);
  __syncthreads();
  if (tid < NEXP) blockhist[blockIdx.x * NEXP + tid] = h[tid];
}

// ---------------- scan: per-expert 128-block prefix (8 waves) ----------------
__global__ __launch_bounds__(512)
void k_scan2(const int* __restrict__ blockhist, int* __restrict__ counts,
             int* __restrict__ offsets, int* __restrict__ tp,
             int* __restrict__ blockbase)
{
  __shared__ int ltot[NEXP];
  __shared__ int loff[NEXP + 1];
  int tid = threadIdx.x;
  int lane = tid & 63, e = tid >> 6;       // 8 waves, one expert each
  int o0 = blockhist[lane * NEXP + e];
  int o1 = blockhist[(64 + lane) * NEXP + e];
  int h0 = o0, h1 = o1;
#pragma unroll
  for (int d = 1; d < 64; d <<= 1) { int v = __shfl_up(h0, d); if (lane >= d) h0 += v; }
  int s0 = __shfl(h0, 63);
#pragma unroll
  for (int d = 1; d < 64; d <<= 1) { int v = __shfl_up(h1, d); if (lane >= d) h1 += v; }
  h1 += s0;
  if (lane == 63) ltot[e] = h1;
  __syncthreads();
  if (tid == 0) {
    loff[0] = 0;
    int tpv = 0; tp[0] = 0;
    for (int k = 0; k < NEXP; ++k) {
      loff[k + 1] = loff[k] + ltot[k];
      counts[k] = ltot[k];
      offsets[k] = loff[k];
      tpv += (ltot[k] + 127) / 128;
      tp[k + 1] = tpv;
    }
    offsets[NEXP] = loff[NEXP];
  }
  __syncthreads();
  int base = loff[e];
  blockbase[lane * NEXP + e]        = base + h0 - o0;   // exclusive prefix
  blockbase[(64 + lane) * NEXP + e] = base + h1 - o1;
}

// ---------------- stable slot assign + gather rows into Xg ----------------
__global__ __launch_bounds__(256)
void k_assign_gather(const float* __restrict__ x, const int* __restrict__ tk_e,
                     const float* __restrict__ tk_w,
                     const int* __restrict__ blockbase,
                     int* __restrict__ slot_token, float* __restrict__ slot_w,
                     unsigned short* __restrict__ Xg)
{
  __shared__ int eh[256];
  __shared__ int sslot[256];
  int b = blockIdx.x, tid = threadIdx.x;
  int pick = b * 256 + tid;
  int e = tk_e[pick];
  eh[tid] = e;
  __syncthreads();
  int rank = 0;
  for (int j = 0; j < tid; ++j) rank += (eh[j] == e);   // LDS broadcast reads
  int slot = blockbase[b * NEXP + e] + rank;
  sslot[tid] = slot;
  slot_token[slot] = pick >> 1;
  slot_w[slot] = tk_w[pick];
  __syncthreads();
  int lane = tid & 63, wid = tid >> 6;
  for (int p = wid * 64; p < wid * 64 + 64; ++p) {
    int token = (b * 256 + p) >> 1;
    int s = sslot[p];
    const float4* src = (const float4*)(x + (size_t)token * CDIM);
    ushort4* dst = (ushort4*)(Xg + (size_t)s * CDIM);
#pragma unroll
    for (int i = 0; i < 3; ++i) {
      float4 v = src[i * 64 + lane];
      ushort4 hh;
      hh.x = f2bf(v.x); hh.y = f2bf(v.y); hh.z = f2bf(v.z); hh.w = f2bf(v.w);
      dst[i * 64 + lane] = hh;
    }
  }
}

// ---------------- grouped GEMM, 128x128 tile, BK=32, 4 waves ----------------
template <int EPI>
__global__ __launch_bounds__(256)
void k_gemm(const unsigned short* __restrict__ A, int lda,
            const unsigned short* __restrict__ B, int ldb, long sB, int bkoff,
            int Ksteps,
            const int* __restrict__ counts, const int* __restrict__ offsets,
            const int* __restrict__ tp,
            int n0base, const float* __restrict__ bias, int biasStride,
            unsigned short* __restrict__ Hout, int ldh,
            float* __restrict__ Out,
            const int* __restrict__ slot_token, const float* __restrict__ slot_w)
{
  __shared__ __align__(16) unsigned short smA[128 * 32];
  __shared__ __align__(16) unsigned short smB[128 * 32];

  int by = blockIdx.y;
  if (by >= tp[NEXP]) return;
  int e = 0;
  while (by >= tp[e + 1]) ++e;
  int rowtile = by - tp[e];
  int m0 = rowtile * 128;
  int cnt = counts[e];
  int rowbase = offsets[e];

  int n0 = blockIdx.x * 128;
  const unsigned short* Bexp = B + (long)e * sB + bkoff + (long)(n0base + n0) * ldb;
  const unsigned short* Aexp = A + (long)(rowbase + m0) * lda;

  int tid = threadIdx.x;
  int lane = tid & 63, wid = tid >> 6;
  int wm = wid >> 1, wn = wid & 1;

  f32x4 acc[4][4] = {};

  int lin0 = tid * 16;
  int rA0 = lin0 >> 6;
  int kA0 = (lin0 & 63) >> 1;
  char* smAb = (char*)smA;
  char* smBb = (char*)smB;
  char* ldsA0 = smAb + wid * 1024;
  char* ldsA1 = smAb + 4096 + wid * 1024;
  char* ldsB0 = smBb + wid * 1024;
  char* ldsB1 = smBb + 4096 + wid * 1024;

  int ar = lane & 15, kg = lane >> 4;

  for (int ks = 0; ks < Ksteps; ++ks) {
    int k0 = ks * 32;
    async16(Aexp + (long)rA0 * lda + k0 + kA0, ldsA0);
    async16(Aexp + (long)(rA0 + 64) * lda + k0 + kA0, ldsA1);
    async16(Bexp + (long)rA0 * ldb + k0 + kA0, ldsB0);
    async16(Bexp + (long)(rA0 + 64) * ldb + k0 + kA0, ldsB1);
    __syncthreads();
    bf16x8 af[4], bfr[4];
#pragma unroll
    for (int i = 0; i < 4; ++i)
      af[i] = *(const bf16x8*)(smA + ((wm * 64 + i * 16 + ar) * 32 + kg * 8));
#pragma unroll
    for (int i = 0; i < 4; ++i)
      bfr[i] = *(const bf16x8*)(smB + ((wn * 64 + i * 16 + ar) * 32 + kg * 8));
#pragma unroll
    for (int mi = 0; mi < 4; ++mi)
#pragma unroll
      for (int ni = 0; ni < 4; ++ni)
        acc[mi][ni] = __builtin_amdgcn_mfma_f32_16x16x32_bf16(af[mi], bfr[ni],
                                                              acc[mi][ni], 0, 0, 0);
    __syncthreads();
  }

  if (EPI == 0) {
#pragma unroll
    for (int ni = 0; ni < 4; ++ni) {
      int ncol = n0 + wn * 64 + ni * 16 + ar;
      float bv = bias[e * biasStride + n0base + ncol];
#pragma unroll
      for (int mi = 0; mi < 4; ++mi) {
#pragma unroll
        for (int r = 0; r < 4; ++r) {
          int row = m0 + wm * 64 + mi * 16 + kg * 4 + r;
          if (row < cnt) {
            float v = acc[mi][ni][r] + bv;
            v = 0.5f * v * (1.0f + erff(v * 0.70710678118654752f));
            Hout[(long)(rowbase + row) * ldh + ncol] = f2bf(v);
          }
        }
      }
    }
  } else {
#pragma unroll
    for (int mi = 0; mi < 4; ++mi) {
#pragma unroll
      for (int r = 0; r < 4; ++r) {
        int row = m0 + wm * 64 + mi * 16 + kg * 4 + r;
        if (row < cnt) {
          int token = slot_token[rowbase + row];
          float wt = slot_w[rowbase + row];
#pragma unroll
          for (int ni = 0; ni < 4; ++ni) {
            int ncol = n0 + wn * 64 + ni * 16 + ar;
            float v = (acc[mi][ni][r] + bias[e * biasStride + ncol]) * wt;
            atomicAdd(&Out[(long)token * CDIM + ncol], v);
          }
        }
      }
    }
  }
}

extern "C" void kernel_launch(void* const* d_in, const int* in_sizes, int n_in,
                              void* d_out, int out_size, void* d_ws, size_t ws_size,
                              hipStream_t stream) {
  const float* x        = (const float*)d_in[0];
  const float* router_w = (const float*)d_in[1];
  const float* w1       = (const float*)d_in[2];
  const float* b1       = (const float*)d_in[3];
  const float* w2       = (const float*)d_in[4];
  const float* b2       = (const float*)d_in[5];
  float* out = (float*)d_out;

  char* ws = (char*)d_ws;
  size_t off = 0;
  auto alloc = [&](size_t bytes) -> void* {
    void* p = ws + off;
    off = (off + bytes + 255) & ~(size_t)255;
    return p;
  };
  int*   counts     = (int*)alloc(NEXP * 4);
  int*   offsets    = (int*)alloc((NEXP + 1) * 4);
  int*   tp         = (int*)alloc((NEXP + 1) * 4);
  int*   tk_e       = (int*)alloc((size_t)NSLOT * 4);
  float* tk_w       = (float*)alloc((size_t)NSLOT * 4);
  int*   blockhist  = (int*)alloc((size_t)HBLK * NEXP * 4);
  int*   blockbase  = (int*)alloc((size_t)HBLK * NEXP * 4);
  int*   slot_token = (int*)alloc((size_t)NSLOT * 4);
  float* slot_w     = (float*)alloc((size_t)NSLOT * 4);
  unsigned short* w1t = (unsigned short*)alloc((size_t)NEXP * FDIM * CDIM * 2);
  unsigned short* w2t = (unsigned short*)alloc((size_t)NEXP * CDIM * FDIM * 2);
  unsigned short* Xg  = (unsigned short*)alloc((size_t)(NSLOT + 128) * CDIM * 2);
  int FC = FDIM;
  while (FC > 768 && off + (size_t)(NSLOT + 128) * FC * 2 > ws_size) FC >>= 1;
  unsigned short* H = (unsigned short*)alloc((size_t)(NSLOT + 128) * FC * 2);

  hipMemsetAsync(out, 0, (size_t)NTOK * CDIM * 4, stream);

  k_transpose<<<dim3(FDIM / 32, CDIM / 32, NEXP), 256, 0, stream>>>(w1, w1t, CDIM, FDIM);
  k_transpose<<<dim3(CDIM / 32, FDIM / 32, NEXP), 256, 0, stream>>>(w2, w2t, FDIM, CDIM);
  k_router<<<NTOK / 4, 256, 0, stream>>>(x, router_w, tk_e, tk_w);
  k_hist<<<HBLK, 256, 0, stream>>>(tk_e, blockhist);
  k_scan2<<<1, 512, 0, stream>>>(blockhist, counts, offsets, tp, blockbase);
  k_assign_gather<<<HBLK, 256, 0, stream>>>(x, tk_e, tk_w, blockbase,
                                            slot_token, slot_w, Xg);

  const int MAXTILES = NSLOT / 128 + NEXP - 1;  // 263
  for (int f0 = 0; f0 < FDIM; f0 += FC) {
    k_gemm<0><<<dim3(FC / 128, MAXTILES), 256, 0, stream>>>(
        Xg, CDIM, w1t, CDIM, (long)FDIM * CDIM, 0, CDIM / 32,
        counts, offsets, tp, f0, b1, FDIM, H, FC, nullptr, nullptr, nullptr);
    k_gemm<1><<<dim3(CDIM / 128, MAXTILES), 256, 0, stream>>>(
        H, FC, w2t, FDIM, (long)CDIM * FDIM, f0, FC / 32,
        counts, offsets, tp, 0, b2, CDIM, nullptr, 0, out, slot_token, slot_w);
  }
}

// Round 3
// 917.493 us; speedup vs baseline: 1.4596x; 1.0696x over previous
//
#include <hip/hip_runtime.h>
#include <hip/hip_bf16.h>

#define NTOK 16384
#define CDIM 768
#define FDIM 3072
#define NEXP 8
#define NSLOT 32768   // NTOK * TOPK
#define HBLK 128      // histogram blocks (NSLOT / 256)

typedef __attribute__((ext_vector_type(8))) short bf16x8;
typedef __attribute__((ext_vector_type(4))) float f32x4;

__device__ __forceinline__ unsigned short f2bf(float f) {
  unsigned int u = __float_as_uint(f);
  u += 0x7FFFu + ((u >> 16) & 1u);   // RNE
  return (unsigned short)(u >> 16);
}

__device__ __forceinline__ void async16(const void* g, void* l) {
  __builtin_amdgcn_global_load_lds(
      (const __attribute__((address_space(1))) unsigned int*)g,
      (__attribute__((address_space(3))) unsigned int*)l, 16, 0, 0);
}

// ---------------- transpose + fp32->bf16 convert ----------------
__global__ __launch_bounds__(256)
void k_transpose(const float* __restrict__ src, unsigned short* __restrict__ dst,
                 int R, int Cc)
{
  __shared__ float tle[32][33];
  int e = blockIdx.z;
  int c0 = blockIdx.x * 32, r0 = blockIdx.y * 32;
  int tx = threadIdx.x & 31, ty = threadIdx.x >> 5;
  const float* s = src + (size_t)e * R * Cc;
  unsigned short* d = dst + (size_t)e * R * Cc;
#pragma unroll
  for (int i = 0; i < 4; ++i)
    tle[ty + i * 8][tx] = s[(size_t)(r0 + ty + i * 8) * Cc + c0 + tx];
  __syncthreads();
#pragma unroll
  for (int i = 0; i < 4; ++i)
    d[(size_t)(c0 + ty + i * 8) * R + r0 + tx] = f2bf(tle[tx][ty + i * 8]);
}

// ---------------- router ----------------
__global__ __launch_bounds__(256)
void k_router(const float* __restrict__ x, const float* __restrict__ rw,
              int* __restrict__ tk_e, float* __restrict__ tk_w)
{
  __shared__ float srw[NEXP * CDIM];
  int tid = threadIdx.x;
#pragma unroll
  for (int i = 0; i < (NEXP * CDIM / 4) / 256; ++i)
    ((float4*)srw)[tid + i * 256] = ((const float4*)rw)[tid + i * 256];
  __syncthreads();
  int lane = tid & 63, wid = tid >> 6;
  int t = blockIdx.x * 4 + wid;
  float a[NEXP];
#pragma unroll
  for (int e = 0; e < NEXP; ++e) a[e] = 0.f;
  const float* xr = x + (size_t)t * CDIM;
#pragma unroll
  for (int c = 0; c < CDIM / 64; ++c) {
    float xv = xr[c * 64 + lane];
#pragma unroll
    for (int e = 0; e < NEXP; ++e) a[e] += xv * srw[e * CDIM + c * 64 + lane];
  }
#pragma unroll
  for (int e = 0; e < NEXP; ++e) {
#pragma unroll
    for (int off = 32; off; off >>= 1) a[e] += __shfl_xor(a[e], off);
  }
  if (lane == 0) {
    int i0 = 0; float l0 = a[0];
#pragma unroll
    for (int e = 1; e < NEXP; ++e) if (a[e] > l0) { l0 = a[e]; i0 = e; }
    int i1 = -1; float l1 = -1e30f;
#pragma unroll
    for (int e = 0; e < NEXP; ++e) if (e != i0 && a[e] > l1) { l1 = a[e]; i1 = e; }
    float w0 = 1.f / (1.f + expf(l1 - l0));
    tk_e[2 * t] = i0;     tk_e[2 * t + 1] = i1;
    tk_w[2 * t] = w0;     tk_w[2 * t + 1] = 1.f - w0;
  }
}

// ---------------- per-block expert histogram ----------------
__global__ __launch_bounds__(256)
void k_hist(const int* __restrict__ tk_e, int* __restrict__ blockhist)
{
  __shared__ int h[NEXP];
  int tid = threadIdx.x;
  if (tid < NEXP) h[tid] = 0;
  __syncthreads();
  int e = tk_e[blockIdx.x * 256 + tid];
  atomicAdd(&h[e], 1);
  __syncthreads();
  if (tid < NEXP) blockhist[blockIdx.x * NEXP + tid] = h[tid];
}

// ---------------- scan ----------------
__global__ __launch_bounds__(512)
void k_scan2(const int* __restrict__ blockhist, int* __restrict__ counts,
             int* __restrict__ offsets, int* __restrict__ tp,
             int* __restrict__ blockbase)
{
  __shared__ int ltot[NEXP];
  __shared__ int loff[NEXP + 1];
  int tid = threadIdx.x;
  int lane = tid & 63, e = tid >> 6;
  int o0 = blockhist[lane * NEXP + e];
  int o1 = blockhist[(64 + lane) * NEXP + e];
  int h0 = o0, h1 = o1;
#pragma unroll
  for (int d = 1; d < 64; d <<= 1) { int v = __shfl_up(h0, d); if (lane >= d) h0 += v; }
  int s0 = __shfl(h0, 63);
#pragma unroll
  for (int d = 1; d < 64; d <<= 1) { int v = __shfl_up(h1, d); if (lane >= d) h1 += v; }
  h1 += s0;
  if (lane == 63) ltot[e] = h1;
  __syncthreads();
  if (tid == 0) {
    loff[0] = 0;
    int tpv = 0; tp[0] = 0;
    for (int k = 0; k < NEXP; ++k) {
      loff[k + 1] = loff[k] + ltot[k];
      counts[k] = ltot[k];
      offsets[k] = loff[k];
      tpv += (ltot[k] + 127) / 128;
      tp[k + 1] = tpv;
    }
    offsets[NEXP] = loff[NEXP];
  }
  __syncthreads();
  int base = loff[e];
  blockbase[lane * NEXP + e]        = base + h0 - o0;
  blockbase[(64 + lane) * NEXP + e] = base + h1 - o1;
}

// ---------------- stable slot assign + gather ----------------
__global__ __launch_bounds__(256)
void k_assign_gather(const float* __restrict__ x, const int* __restrict__ tk_e,
                     const float* __restrict__ tk_w,
                     const int* __restrict__ blockbase,
                     int* __restrict__ slot_token, float* __restrict__ slot_w,
                     unsigned short* __restrict__ Xg)
{
  __shared__ int eh[256];
  __shared__ int sslot[256];
  int b = blockIdx.x, tid = threadIdx.x;
  int pick = b * 256 + tid;
  int e = tk_e[pick];
  eh[tid] = e;
  __syncthreads();
  int rank = 0;
  for (int j = 0; j < tid; ++j) rank += (eh[j] == e);
  int slot = blockbase[b * NEXP + e] + rank;
  sslot[tid] = slot;
  slot_token[slot] = pick >> 1;
  slot_w[slot] = tk_w[pick];
  __syncthreads();
  int lane = tid & 63, wid = tid >> 6;
  for (int p = wid * 64; p < wid * 64 + 64; ++p) {
    int token = (b * 256 + p) >> 1;
    int s = sslot[p];
    const float4* src = (const float4*)(x + (size_t)token * CDIM);
    ushort4* dst = (ushort4*)(Xg + (size_t)s * CDIM);
#pragma unroll
    for (int i = 0; i < 3; ++i) {
      float4 v = src[i * 64 + lane];
      ushort4 hh;
      hh.x = f2bf(v.x); hh.y = f2bf(v.y); hh.z = f2bf(v.z); hh.w = f2bf(v.w);
      dst[i * 64 + lane] = hh;
    }
  }
}

// ---------------- grouped GEMM: 128x128 tile, BK=32, depth-3 pipeline -------
// LDS ring: 5 bufs x (8KB A + 8KB B) = 80 KB. One s_barrier per K-step,
// counted vmcnt (never 0 mid-loop). XOR-swizzled LDS via pre-swizzled source.
template <int EPI>
__device__ __forceinline__ void gemm_body(
    const unsigned short* __restrict__ A, int lda,
    const unsigned short* __restrict__ B, int ldb, long sB, int bkoff,
    int Ksteps,
    const int* __restrict__ counts, const int* __restrict__ offsets,
    const int* __restrict__ tp,
    int n0base, const float* __restrict__ bias, int biasStride,
    unsigned short* __restrict__ Hout, int ldh,
    float* __restrict__ Out,
    const int* __restrict__ slot_token, const float* __restrict__ slot_w,
    int gx, int nwg)
{
  __shared__ __align__(16) char lds[5 * 16384];

  // XCD-aware bijective swizzle (m204) on flattened block id
  int orig = blockIdx.y * gx + blockIdx.x;
  int q = nwg >> 3, r = nwg & 7;
  int xcd = orig & 7, j = orig >> 3;
  int wgid = (xcd < r ? xcd * (q + 1) : r * (q + 1) + (xcd - r) * q) + j;
  int bx = wgid % gx, by = wgid / gx;

  if (by >= tp[NEXP]) return;
  int e = 0;
  while (by >= tp[e + 1]) ++e;
  int m0 = (by - tp[e]) * 128;
  int cnt = counts[e];
  int rowbase = offsets[e];
  int n0 = bx * 128;
  const unsigned short* Bexp = B + (long)e * sB + bkoff + (long)(n0base + n0) * ldb;
  const unsigned short* Aexp = A + (long)(rowbase + m0) * lda;

  int tid = threadIdx.x;
  int lane = tid & 63, wid = tid >> 6;
  int wm = wid >> 1, wn = wid & 1;
  int ar = lane & 15, kg = lane >> 4;
  int kgs = (kg ^ ((ar >> 1) & 3)) << 4;   // swizzled 16B-chunk byte offset

  // staging source: pre-swizzle the k-chunk so linear LDS dest = swizzled tile
  int rA0 = tid >> 2;                       // LDS row 0..63
  int cA0 = tid & 3;                        // 16B chunk within row
  int ksw = (cA0 ^ ((rA0 >> 1) & 3)) << 3;  // element offset in 32-elem window
  const unsigned short* As0 = Aexp + (long)rA0 * lda + ksw;
  const unsigned short* As1 = Aexp + (long)(rA0 + 64) * lda + ksw;
  const unsigned short* Bs0 = Bexp + (long)rA0 * ldb + ksw;
  const unsigned short* Bs1 = Bexp + (long)(rA0 + 64) * ldb + ksw;

  f32x4 acc[4][4] = {};

  auto STAGE = [&](int t) {
    char* bb = lds + (t % 5) * 16384;
    int ko = t * 32;
    async16(As0 + ko, bb + wid * 1024);
    async16(As1 + ko, bb + 4096 + wid * 1024);
    async16(Bs0 + ko, bb + 8192 + wid * 1024);
    async16(Bs1 + ko, bb + 12288 + wid * 1024);
  };

  STAGE(0); STAGE(1); STAGE(2);   // Ksteps >= 24 always

  for (int ks = 0; ks < Ksteps; ++ks) {
    if (ks + 3 < Ksteps) {
      STAGE(ks + 3);
      asm volatile("s_waitcnt vmcnt(12)" ::: "memory");
    } else if (ks + 2 < Ksteps) {
      asm volatile("s_waitcnt vmcnt(8)" ::: "memory");
    } else if (ks + 1 < Ksteps) {
      asm volatile("s_waitcnt vmcnt(4)" ::: "memory");
    } else {
      asm volatile("s_waitcnt vmcnt(0)" ::: "memory");
    }
    __builtin_amdgcn_s_barrier();
    asm volatile("" ::: "memory");   // keep ds_reads below the barrier

    const char* bb = lds + (ks % 5) * 16384;
    const char* bA = bb + (wm * 64 + ar) * 64 + kgs;
    const char* bB = bb + 8192 + (wn * 64 + ar) * 64 + kgs;
    bf16x8 af[4], bfr[4];
#pragma unroll
    for (int i = 0; i < 4; ++i) af[i] = *(const bf16x8*)(bA + i * 1024);
#pragma unroll
    for (int i = 0; i < 4; ++i) bfr[i] = *(const bf16x8*)(bB + i * 1024);
#pragma unroll
    for (int mi = 0; mi < 4; ++mi)
#pragma unroll
      for (int ni = 0; ni < 4; ++ni)
        acc[mi][ni] = __builtin_amdgcn_mfma_f32_16x16x32_bf16(af[mi], bfr[ni],
                                                              acc[mi][ni], 0, 0, 0);
  }

  if (EPI == 0) {
#pragma unroll
    for (int ni = 0; ni < 4; ++ni) {
      int ncol = n0 + wn * 64 + ni * 16 + ar;
      float bv = bias[e * biasStride + n0base + ncol];
#pragma unroll
      for (int mi = 0; mi < 4; ++mi) {
#pragma unroll
        for (int r = 0; r < 4; ++r) {
          int row = m0 + wm * 64 + mi * 16 + kg * 4 + r;
          if (row < cnt) {
            float v = acc[mi][ni][r] + bv;
            v = 0.5f * v * (1.0f + erff(v * 0.70710678118654752f));
            Hout[(long)(rowbase + row) * ldh + ncol] = f2bf(v);
          }
        }
      }
    }
  } else {
#pragma unroll
    for (int mi = 0; mi < 4; ++mi) {
#pragma unroll
      for (int r = 0; r < 4; ++r) {
        int row = m0 + wm * 64 + mi * 16 + kg * 4 + r;
        if (row < cnt) {
          int token = slot_token[rowbase + row];
          float wt = slot_w[rowbase + row];
#pragma unroll
          for (int ni = 0; ni < 4; ++ni) {
            int ncol = n0 + wn * 64 + ni * 16 + ar;
            float v = (acc[mi][ni][r] + bias[e * biasStride + ncol]) * wt;
            atomicAdd(&Out[(long)token * CDIM + ncol], v);
          }
        }
      }
    }
  }
}

__global__ __launch_bounds__(256)
void k_gemm1(const unsigned short* __restrict__ A, int lda,
             const unsigned short* __restrict__ B, int ldb, long sB, int bkoff,
             int Ksteps, const int* __restrict__ counts,
             const int* __restrict__ offsets, const int* __restrict__ tp,
             int n0base, const float* __restrict__ bias, int biasStride,
             unsigned short* __restrict__ Hout, int ldh, int gx, int nwg)
{
  gemm_body<0>(A, lda, B, ldb, sB, bkoff, Ksteps, counts, offsets, tp,
               n0base, bias, biasStride, Hout, ldh, nullptr, nullptr, nullptr,
               gx, nwg);
}

__global__ __launch_bounds__(256)
void k_gemm2(const unsigned short* __restrict__ A, int lda,
             const unsigned short* __restrict__ B, int ldb, long sB, int bkoff,
             int Ksteps, const int* __restrict__ counts,
             const int* __restrict__ offsets, const int* __restrict__ tp,
             const float* __restrict__ bias, int biasStride,
             float* __restrict__ Out, const int* __restrict__ slot_token,
             const float* __restrict__ slot_w, int gx, int nwg)
{
  gemm_body<1>(A, lda, B, ldb, sB, bkoff, Ksteps, counts, offsets, tp,
               0, bias, biasStride, nullptr, 0, Out, slot_token, slot_w,
               gx, nwg);
}

extern "C" void kernel_launch(void* const* d_in, const int* in_sizes, int n_in,
                              void* d_out, int out_size, void* d_ws, size_t ws_size,
                              hipStream_t stream) {
  const float* x        = (const float*)d_in[0];
  const float* router_w = (const float*)d_in[1];
  const float* w1       = (const float*)d_in[2];
  const float* b1       = (const float*)d_in[3];
  const float* w2       = (const float*)d_in[4];
  const float* b2       = (const float*)d_in[5];
  float* out = (float*)d_out;

  char* ws = (char*)d_ws;
  size_t off = 0;
  auto alloc = [&](size_t bytes) -> void* {
    void* p = ws + off;
    off = (off + bytes + 255) & ~(size_t)255;
    return p;
  };
  int*   counts     = (int*)alloc(NEXP * 4);
  int*   offsets    = (int*)alloc((NEXP + 1) * 4);
  int*   tp         = (int*)alloc((NEXP + 1) * 4);
  int*   tk_e       = (int*)alloc((size_t)NSLOT * 4);
  float* tk_w       = (float*)alloc((size_t)NSLOT * 4);
  int*   blockhist  = (int*)alloc((size_t)HBLK * NEXP * 4);
  int*   blockbase  = (int*)alloc((size_t)HBLK * NEXP * 4);
  int*   slot_token = (int*)alloc((size_t)NSLOT * 4);
  float* slot_w     = (float*)alloc((size_t)NSLOT * 4);
  unsigned short* w1t = (unsigned short*)alloc((size_t)NEXP * FDIM * CDIM * 2);
  unsigned short* w2t = (unsigned short*)alloc((size_t)NEXP * CDIM * FDIM * 2);
  unsigned short* Xg  = (unsigned short*)alloc((size_t)(NSLOT + 128) * CDIM * 2);
  int FC = FDIM;
  while (FC > 768 && off + (size_t)(NSLOT + 128) * FC * 2 > ws_size) FC >>= 1;
  unsigned short* H = (unsigned short*)alloc((size_t)(NSLOT + 128) * FC * 2);

  hipMemsetAsync(out, 0, (size_t)NTOK * CDIM * 4, stream);

  k_transpose<<<dim3(FDIM / 32, CDIM / 32, NEXP), 256, 0, stream>>>(w1, w1t, CDIM, FDIM);
  k_transpose<<<dim3(CDIM / 32, FDIM / 32, NEXP), 256, 0, stream>>>(w2, w2t, FDIM, CDIM);
  k_router<<<NTOK / 4, 256, 0, stream>>>(x, router_w, tk_e, tk_w);
  k_hist<<<HBLK, 256, 0, stream>>>(tk_e, blockhist);
  k_scan2<<<1, 512, 0, stream>>>(blockhist, counts, offsets, tp, blockbase);
  k_assign_gather<<<HBLK, 256, 0, stream>>>(x, tk_e, tk_w, blockbase,
                                            slot_token, slot_w, Xg);

  const int MAXTILES = NSLOT / 128 + NEXP - 1;  // 263
  for (int f0 = 0; f0 < FDIM; f0 += FC) {
    int gx1 = FC / 128;
    k_gemm1<<<dim3(gx1, MAXTILES), 256, 0, stream>>>(
        Xg, CDIM, w1t, CDIM, (long)FDIM * CDIM, 0, CDIM / 32,
        counts, offsets, tp, f0, b1, FDIM, H, FC, gx1, gx1 * MAXTILES);
    int gx2 = CDIM / 128;
    k_gemm2<<<dim3(gx2, MAXTILES), 256, 0, stream>>>(
        H, FC, w2t, FDIM, (long)CDIM * FDIM, f0, FC / 32,
        counts, offsets, tp, b2, CDIM, out, slot_token, slot_w,
        gx2, gx2 * MAXTILES);
  }
}

// Round 4
// 901.057 us; speedup vs baseline: 1.4862x; 1.0182x over previous
//
#include <hip/hip_runtime.h>
#include <hip/hip_bf16.h>

#define NTOK 16384
#define CDIM 768
#define FDIM 3072
#define NEXP 8
#define NSLOT 32768   // NTOK * TOPK
#define HBLK 128      // histogram blocks (NSLOT / 256)

typedef __attribute__((ext_vector_type(8))) short bf16x8;
typedef __attribute__((ext_vector_type(4))) float f32x4;

__device__ __forceinline__ unsigned short f2bf(float f) {
  unsigned int u = __float_as_uint(f);
  u += 0x7FFFu + ((u >> 16) & 1u);   // RNE
  return (unsigned short)(u >> 16);
}

__device__ __forceinline__ void async16(const void* g, void* l) {
  __builtin_amdgcn_global_load_lds(
      (const __attribute__((address_space(1))) unsigned int*)g,
      (__attribute__((address_space(3))) unsigned int*)l, 16, 0, 0);
}

// ---------------- transpose + fp32->bf16 convert ----------------
__global__ __launch_bounds__(256)
void k_transpose(const float* __restrict__ src, unsigned short* __restrict__ dst,
                 int R, int Cc)
{
  __shared__ float tle[32][33];
  int e = blockIdx.z;
  int c0 = blockIdx.x * 32, r0 = blockIdx.y * 32;
  int tx = threadIdx.x & 31, ty = threadIdx.x >> 5;
  const float* s = src + (size_t)e * R * Cc;
  unsigned short* d = dst + (size_t)e * R * Cc;
#pragma unroll
  for (int i = 0; i < 4; ++i)
    tle[ty + i * 8][tx] = s[(size_t)(r0 + ty + i * 8) * Cc + c0 + tx];
  __syncthreads();
#pragma unroll
  for (int i = 0; i < 4; ++i)
    d[(size_t)(c0 + ty + i * 8) * R + r0 + tx] = f2bf(tle[tx][ty + i * 8]);
}

// ---------------- router ----------------
__global__ __launch_bounds__(256)
void k_router(const float* __restrict__ x, const float* __restrict__ rw,
              int* __restrict__ tk_e, float* __restrict__ tk_w)
{
  __shared__ float srw[NEXP * CDIM];
  int tid = threadIdx.x;
#pragma unroll
  for (int i = 0; i < (NEXP * CDIM / 4) / 256; ++i)
    ((float4*)srw)[tid + i * 256] = ((const float4*)rw)[tid + i * 256];
  __syncthreads();
  int lane = tid & 63, wid = tid >> 6;
  int t = blockIdx.x * 4 + wid;
  float a[NEXP];
#pragma unroll
  for (int e = 0; e < NEXP; ++e) a[e] = 0.f;
  const float* xr = x + (size_t)t * CDIM;
#pragma unroll
  for (int c = 0; c < CDIM / 64; ++c) {
    float xv = xr[c * 64 + lane];
#pragma unroll
    for (int e = 0; e < NEXP; ++e) a[e] += xv * srw[e * CDIM + c * 64 + lane];
  }
#pragma unroll
  for (int e = 0; e < NEXP; ++e) {
#pragma unroll
    for (int off = 32; off; off >>= 1) a[e] += __shfl_xor(a[e], off);
  }
  if (lane == 0) {
    int i0 = 0; float l0 = a[0];
#pragma unroll
    for (int e = 1; e < NEXP; ++e) if (a[e] > l0) { l0 = a[e]; i0 = e; }
    int i1 = -1; float l1 = -1e30f;
#pragma unroll
    for (int e = 0; e < NEXP; ++e) if (e != i0 && a[e] > l1) { l1 = a[e]; i1 = e; }
    float w0 = 1.f / (1.f + expf(l1 - l0));
    tk_e[2 * t] = i0;     tk_e[2 * t + 1] = i1;
    tk_w[2 * t] = w0;     tk_w[2 * t + 1] = 1.f - w0;
  }
}

// ---------------- per-block expert histogram ----------------
__global__ __launch_bounds__(256)
void k_hist(const int* __restrict__ tk_e, int* __restrict__ blockhist)
{
  __shared__ int h[NEXP];
  int tid = threadIdx.x;
  if (tid < NEXP) h[tid] = 0;
  __syncthreads();
  int e = tk_e[blockIdx.x * 256 + tid];
  atomicAdd(&h[e], 1);
  __syncthreads();
  if (tid < NEXP) blockhist[blockIdx.x * NEXP + tid] = h[tid];
}

// ---------------- scan ----------------
__global__ __launch_bounds__(512)
void k_scan2(const int* __restrict__ blockhist, int* __restrict__ counts,
             int* __restrict__ offsets, int* __restrict__ tp,
             int* __restrict__ blockbase)
{
  __shared__ int ltot[NEXP];
  __shared__ int loff[NEXP + 1];
  int tid = threadIdx.x;
  int lane = tid & 63, e = tid >> 6;
  int o0 = blockhist[lane * NEXP + e];
  int o1 = blockhist[(64 + lane) * NEXP + e];
  int h0 = o0, h1 = o1;
#pragma unroll
  for (int d = 1; d < 64; d <<= 1) { int v = __shfl_up(h0, d); if (lane >= d) h0 += v; }
  int s0 = __shfl(h0, 63);
#pragma unroll
  for (int d = 1; d < 64; d <<= 1) { int v = __shfl_up(h1, d); if (lane >= d) h1 += v; }
  h1 += s0;
  if (lane == 63) ltot[e] = h1;
  __syncthreads();
  if (tid == 0) {
    loff[0] = 0;
    int tpv = 0; tp[0] = 0;
    for (int k = 0; k < NEXP; ++k) {
      loff[k + 1] = loff[k] + ltot[k];
      counts[k] = ltot[k];
      offsets[k] = loff[k];
      tpv += (ltot[k] + 127) / 128;
      tp[k + 1] = tpv;
    }
    offsets[NEXP] = loff[NEXP];
  }
  __syncthreads();
  int base = loff[e];
  blockbase[lane * NEXP + e]        = base + h0 - o0;
  blockbase[(64 + lane) * NEXP + e] = base + h1 - o1;
}

// ---------------- stable slot assign + gather ----------------
__global__ __launch_bounds__(256)
void k_assign_gather(const float* __restrict__ x, const int* __restrict__ tk_e,
                     const float* __restrict__ tk_w,
                     const int* __restrict__ blockbase,
                     int* __restrict__ slot_token, float* __restrict__ slot_w,
                     unsigned short* __restrict__ Xg)
{
  __shared__ int eh[256];
  __shared__ int sslot[256];
  int b = blockIdx.x, tid = threadIdx.x;
  int pick = b * 256 + tid;
  int e = tk_e[pick];
  eh[tid] = e;
  __syncthreads();
  int rank = 0;
  for (int j = 0; j < tid; ++j) rank += (eh[j] == e);
  int slot = blockbase[b * NEXP + e] + rank;
  sslot[tid] = slot;
  slot_token[slot] = pick;        // 2*token + kk  (kk=0 primary, 1 secondary)
  slot_w[slot] = tk_w[pick];
  __syncthreads();
  int lane = tid & 63, wid = tid >> 6;
  for (int p = wid * 64; p < wid * 64 + 64; ++p) {
    int token = (b * 256 + p) >> 1;
    int s = sslot[p];
    const float4* src = (const float4*)(x + (size_t)token * CDIM);
    ushort4* dst = (ushort4*)(Xg + (size_t)s * CDIM);
#pragma unroll
    for (int i = 0; i < 3; ++i) {
      float4 v = src[i * 64 + lane];
      ushort4 hh;
      hh.x = f2bf(v.x); hh.y = f2bf(v.y); hh.z = f2bf(v.z); hh.w = f2bf(v.w);
      dst[i * 64 + lane] = hh;
    }
  }
}

// ---------------- grouped GEMM: 128x128 tile, BK=32, depth-3 pipeline -------
// EPI==0: H = bf16(gelu(acc + b1))
// EPI==1: partial = acc*wt (+ b2*wt on first chunk); primary->Out, secondary->Ysec
//         first chunk: plain store; later chunks: plain RMW add. No atomics.
template <int EPI>
__device__ __forceinline__ void gemm_body(
    const unsigned short* __restrict__ A, int lda,
    const unsigned short* __restrict__ B, int ldb, long sB, int bkoff,
    int Ksteps,
    const int* __restrict__ counts, const int* __restrict__ offsets,
    const int* __restrict__ tp,
    int n0base, const float* __restrict__ bias, int biasStride,
    unsigned short* __restrict__ Hout, int ldh,
    float* __restrict__ Out, float* __restrict__ Ysec, int first,
    const int* __restrict__ slot_token, const float* __restrict__ slot_w,
    int gx, int nwg)
{
  __shared__ __align__(16) char lds[5 * 16384];

  int orig = blockIdx.y * gx + blockIdx.x;
  int q = nwg >> 3, r = nwg & 7;
  int xcd = orig & 7, j = orig >> 3;
  int wgid = (xcd < r ? xcd * (q + 1) : r * (q + 1) + (xcd - r) * q) + j;
  int bx = wgid % gx, by = wgid / gx;

  if (by >= tp[NEXP]) return;
  int e = 0;
  while (by >= tp[e + 1]) ++e;
  int m0 = (by - tp[e]) * 128;
  int cnt = counts[e];
  int rowbase = offsets[e];
  int n0 = bx * 128;
  const unsigned short* Bexp = B + (long)e * sB + bkoff + (long)(n0base + n0) * ldb;
  const unsigned short* Aexp = A + (long)(rowbase + m0) * lda;

  int tid = threadIdx.x;
  int lane = tid & 63, wid = tid >> 6;
  int wm = wid >> 1, wn = wid & 1;
  int ar = lane & 15, kg = lane >> 4;
  int kgs = (kg ^ ((ar >> 1) & 3)) << 4;

  int rA0 = tid >> 2;
  int cA0 = tid & 3;
  int ksw = (cA0 ^ ((rA0 >> 1) & 3)) << 3;
  const unsigned short* As0 = Aexp + (long)rA0 * lda + ksw;
  const unsigned short* As1 = Aexp + (long)(rA0 + 64) * lda + ksw;
  const unsigned short* Bs0 = Bexp + (long)rA0 * ldb + ksw;
  const unsigned short* Bs1 = Bexp + (long)(rA0 + 64) * ldb + ksw;

  f32x4 acc[4][4] = {};

  auto STAGE = [&](int t) {
    char* bb = lds + (t % 5) * 16384;
    int ko = t * 32;
    async16(As0 + ko, bb + wid * 1024);
    async16(As1 + ko, bb + 4096 + wid * 1024);
    async16(Bs0 + ko, bb + 8192 + wid * 1024);
    async16(Bs1 + ko, bb + 12288 + wid * 1024);
  };

  STAGE(0); STAGE(1); STAGE(2);

  for (int ks = 0; ks < Ksteps; ++ks) {
    if (ks + 3 < Ksteps) {
      STAGE(ks + 3);
      asm volatile("s_waitcnt vmcnt(12)" ::: "memory");
    } else if (ks + 2 < Ksteps) {
      asm volatile("s_waitcnt vmcnt(8)" ::: "memory");
    } else if (ks + 1 < Ksteps) {
      asm volatile("s_waitcnt vmcnt(4)" ::: "memory");
    } else {
      asm volatile("s_waitcnt vmcnt(0)" ::: "memory");
    }
    __builtin_amdgcn_s_barrier();
    asm volatile("" ::: "memory");

    const char* bb = lds + (ks % 5) * 16384;
    const char* bA = bb + (wm * 64 + ar) * 64 + kgs;
    const char* bB = bb + 8192 + (wn * 64 + ar) * 64 + kgs;
    bf16x8 af[4], bfr[4];
#pragma unroll
    for (int i = 0; i < 4; ++i) af[i] = *(const bf16x8*)(bA + i * 1024);
#pragma unroll
    for (int i = 0; i < 4; ++i) bfr[i] = *(const bf16x8*)(bB + i * 1024);
#pragma unroll
    for (int mi = 0; mi < 4; ++mi)
#pragma unroll
      for (int ni = 0; ni < 4; ++ni)
        acc[mi][ni] = __builtin_amdgcn_mfma_f32_16x16x32_bf16(af[mi], bfr[ni],
                                                              acc[mi][ni], 0, 0, 0);
  }

  if (EPI == 0) {
#pragma unroll
    for (int ni = 0; ni < 4; ++ni) {
      int ncol = n0 + wn * 64 + ni * 16 + ar;
      float bv = bias[e * biasStride + n0base + ncol];
#pragma unroll
      for (int mi = 0; mi < 4; ++mi) {
#pragma unroll
        for (int r = 0; r < 4; ++r) {
          int row = m0 + wm * 64 + mi * 16 + kg * 4 + r;
          if (row < cnt) {
            float v = acc[mi][ni][r] + bv;
            v = 0.5f * v * (1.0f + erff(v * 0.70710678118654752f));
            Hout[(long)(rowbase + row) * ldh + ncol] = f2bf(v);
          }
        }
      }
    }
  } else {
    float bscale = first ? 1.0f : 0.0f;
#pragma unroll
    for (int mi = 0; mi < 4; ++mi) {
#pragma unroll
      for (int r = 0; r < 4; ++r) {
        int row = m0 + wm * 64 + mi * 16 + kg * 4 + r;
        if (row < cnt) {
          int st = slot_token[rowbase + row];
          float wt = slot_w[rowbase + row];
          float* dst = ((st & 1) ? Ysec : Out) + (long)(st >> 1) * CDIM;
#pragma unroll
          for (int ni = 0; ni < 4; ++ni) {
            int ncol = n0 + wn * 64 + ni * 16 + ar;
            float v = (acc[mi][ni][r] + bias[e * biasStride + ncol] * bscale) * wt;
            if (first) dst[ncol] = v;
            else       dst[ncol] += v;
          }
        }
      }
    }
  }
}

__global__ __launch_bounds__(256)
void k_gemm1(const unsigned short* __restrict__ A, int lda,
             const unsigned short* __restrict__ B, int ldb, long sB, int bkoff,
             int Ksteps, const int* __restrict__ counts,
             const int* __restrict__ offsets, const int* __restrict__ tp,
             int n0base, const float* __restrict__ bias, int biasStride,
             unsigned short* __restrict__ Hout, int ldh, int gx, int nwg)
{
  gemm_body<0>(A, lda, B, ldb, sB, bkoff, Ksteps, counts, offsets, tp,
               n0base, bias, biasStride, Hout, ldh,
               nullptr, nullptr, 0, nullptr, nullptr, gx, nwg);
}

__global__ __launch_bounds__(256)
void k_gemm2(const unsigned short* __restrict__ A, int lda,
             const unsigned short* __restrict__ B, int ldb, long sB, int bkoff,
             int Ksteps, const int* __restrict__ counts,
             const int* __restrict__ offsets, const int* __restrict__ tp,
             const float* __restrict__ bias, int biasStride,
             float* __restrict__ Out, float* __restrict__ Ysec, int first,
             const int* __restrict__ slot_token, const float* __restrict__ slot_w,
             int gx, int nwg)
{
  gemm_body<1>(A, lda, B, ldb, sB, bkoff, Ksteps, counts, offsets, tp,
               0, bias, biasStride, nullptr, 0,
               Out, Ysec, first, slot_token, slot_w, gx, nwg);
}

// ---------------- final combine: out += ysec ----------------
__global__ __launch_bounds__(256)
void k_combine(float* __restrict__ out, const float* __restrict__ ysec)
{
  int i = blockIdx.x * 256 + threadIdx.x;
  float4 a = ((float4*)out)[i];
  float4 b = ((const float4*)ysec)[i];
  a.x += b.x; a.y += b.y; a.z += b.z; a.w += b.w;
  ((float4*)out)[i] = a;
}

extern "C" void kernel_launch(void* const* d_in, const int* in_sizes, int n_in,
                              void* d_out, int out_size, void* d_ws, size_t ws_size,
                              hipStream_t stream) {
  const float* x        = (const float*)d_in[0];
  const float* router_w = (const float*)d_in[1];
  const float* w1       = (const float*)d_in[2];
  const float* b1       = (const float*)d_in[3];
  const float* w2       = (const float*)d_in[4];
  const float* b2       = (const float*)d_in[5];
  float* out = (float*)d_out;

  char* ws = (char*)d_ws;
  size_t off = 0;
  auto alloc = [&](size_t bytes) -> void* {
    void* p = ws + off;
    off = (off + bytes + 255) & ~(size_t)255;
    return p;
  };
  int*   counts     = (int*)alloc(NEXP * 4);
  int*   offsets    = (int*)alloc((NEXP + 1) * 4);
  int*   tp         = (int*)alloc((NEXP + 1) * 4);
  int*   tk_e       = (int*)alloc((size_t)NSLOT * 4);
  float* tk_w       = (float*)alloc((size_t)NSLOT * 4);
  int*   blockhist  = (int*)alloc((size_t)HBLK * NEXP * 4);
  int*   blockbase  = (int*)alloc((size_t)HBLK * NEXP * 4);
  int*   slot_token = (int*)alloc((size_t)NSLOT * 4);
  float* slot_w     = (float*)alloc((size_t)NSLOT * 4);
  float* ysec       = (float*)alloc((size_t)NTOK * CDIM * 4);
  unsigned short* w1t = (unsigned short*)alloc((size_t)NEXP * FDIM * CDIM * 2);
  unsigned short* w2t = (unsigned short*)alloc((size_t)NEXP * CDIM * FDIM * 2);
  unsigned short* Xg  = (unsigned short*)alloc((size_t)(NSLOT + 128) * CDIM * 2);
  int FC = FDIM;
  while (FC > 192 && off + (size_t)(NSLOT + 128) * FC * 2 > ws_size) FC >>= 1;
  unsigned short* H = (unsigned short*)alloc((size_t)(NSLOT + 128) * FC * 2);

  k_transpose<<<dim3(FDIM / 32, CDIM / 32, NEXP), 256, 0, stream>>>(w1, w1t, CDIM, FDIM);
  k_transpose<<<dim3(CDIM / 32, FDIM / 32, NEXP), 256, 0, stream>>>(w2, w2t, FDIM, CDIM);
  k_router<<<NTOK / 4, 256, 0, stream>>>(x, router_w, tk_e, tk_w);
  k_hist<<<HBLK, 256, 0, stream>>>(tk_e, blockhist);
  k_scan2<<<1, 512, 0, stream>>>(blockhist, counts, offsets, tp, blockbase);
  k_assign_gather<<<HBLK, 256, 0, stream>>>(x, tk_e, tk_w, blockbase,
                                            slot_token, slot_w, Xg);

  const int MAXTILES = NSLOT / 128 + NEXP - 1;  // 263
  for (int f0 = 0; f0 < FDIM; f0 += FC) {
    int gx1 = FC / 128;
    k_gemm1<<<dim3(gx1, MAXTILES), 256, 0, stream>>>(
        Xg, CDIM, w1t, CDIM, (long)FDIM * CDIM, 0, CDIM / 32,
        counts, offsets, tp, f0, b1, FDIM, H, FC, gx1, gx1 * MAXTILES);
    int gx2 = CDIM / 128;
    k_gemm2<<<dim3(gx2, MAXTILES), 256, 0, stream>>>(
        H, FC, w2t, FDIM, (long)CDIM * FDIM, f0, FC / 32,
        counts, offsets, tp, b2, CDIM, out, ysec, (f0 == 0) ? 1 : 0,
        slot_token, slot_w, gx2, gx2 * MAXTILES);
  }
  k_combine<<<NTOK * CDIM / 4 / 256, 256, 0, stream>>>(out, ysec);
}

// Round 5
// 752.183 us; speedup vs baseline: 1.7804x; 1.1979x over previous
//
#include <hip/hip_runtime.h>
#include <hip/hip_bf16.h>

#define NTOK 16384
#define CDIM 768
#define FDIM 3072
#define NEXP 8
#define NSLOT 32768   // NTOK * TOPK
#define HBLK 128      // histogram blocks (NSLOT / 256)
#define MAXTILES 263  // NSLOT/128 + NEXP - 1

typedef __attribute__((ext_vector_type(8))) short bf16x8;
typedef __attribute__((ext_vector_type(4))) float f32x4;

__device__ __forceinline__ unsigned short f2bf(float f) {
  unsigned int u = __float_as_uint(f);
  u += 0x7FFFu + ((u >> 16) & 1u);   // RNE
  return (unsigned short)(u >> 16);
}
__device__ __forceinline__ float bf2f(unsigned short h) {
  return __uint_as_float((unsigned int)h << 16);
}

__device__ __forceinline__ void async16(const void* g, void* l) {
  __builtin_amdgcn_global_load_lds(
      (const __attribute__((address_space(1))) unsigned int*)g,
      (__attribute__((address_space(3))) unsigned int*)l, 16, 0, 0);
}

// ---------------- transpose + fp32->bf16 convert ----------------
__global__ __launch_bounds__(256)
void k_transpose(const float* __restrict__ src, unsigned short* __restrict__ dst,
                 int R, int Cc)
{
  __shared__ float tle[32][33];
  int e = blockIdx.z;
  int c0 = blockIdx.x * 32, r0 = blockIdx.y * 32;
  int tx = threadIdx.x & 31, ty = threadIdx.x >> 5;
  const float* s = src + (size_t)e * R * Cc;
  unsigned short* d = dst + (size_t)e * R * Cc;
#pragma unroll
  for (int i = 0; i < 4; ++i)
    tle[ty + i * 8][tx] = s[(size_t)(r0 + ty + i * 8) * Cc + c0 + tx];
  __syncthreads();
#pragma unroll
  for (int i = 0; i < 4; ++i)
    d[(size_t)(c0 + ty + i * 8) * R + r0 + tx] = f2bf(tle[tx][ty + i * 8]);
}

// ---------------- router ----------------
__global__ __launch_bounds__(256)
void k_router(const float* __restrict__ x, const float* __restrict__ rw,
              int* __restrict__ tk_e, float* __restrict__ tk_w)
{
  __shared__ float srw[NEXP * CDIM];
  int tid = threadIdx.x;
#pragma unroll
  for (int i = 0; i < (NEXP * CDIM / 4) / 256; ++i)
    ((float4*)srw)[tid + i * 256] = ((const float4*)rw)[tid + i * 256];
  __syncthreads();
  int lane = tid & 63, wid = tid >> 6;
  int t = blockIdx.x * 4 + wid;
  float a[NEXP];
#pragma unroll
  for (int e = 0; e < NEXP; ++e) a[e] = 0.f;
  const float* xr = x + (size_t)t * CDIM;
#pragma unroll
  for (int c = 0; c < CDIM / 64; ++c) {
    float xv = xr[c * 64 + lane];
#pragma unroll
    for (int e = 0; e < NEXP; ++e) a[e] += xv * srw[e * CDIM + c * 64 + lane];
  }
#pragma unroll
  for (int e = 0; e < NEXP; ++e) {
#pragma unroll
    for (int off = 32; off; off >>= 1) a[e] += __shfl_xor(a[e], off);
  }
  if (lane == 0) {
    int i0 = 0; float l0 = a[0];
#pragma unroll
    for (int e = 1; e < NEXP; ++e) if (a[e] > l0) { l0 = a[e]; i0 = e; }
    int i1 = -1; float l1 = -1e30f;
#pragma unroll
    for (int e = 0; e < NEXP; ++e) if (e != i0 && a[e] > l1) { l1 = a[e]; i1 = e; }
    float w0 = 1.f / (1.f + expf(l1 - l0));
    tk_e[2 * t] = i0;     tk_e[2 * t + 1] = i1;
    tk_w[2 * t] = w0;     tk_w[2 * t + 1] = 1.f - w0;
  }
}

// ---------------- per-block expert histogram ----------------
__global__ __launch_bounds__(256)
void k_hist(const int* __restrict__ tk_e, int* __restrict__ blockhist)
{
  __shared__ int h[NEXP];
  int tid = threadIdx.x;
  if (tid < NEXP) h[tid] = 0;
  __syncthreads();
  int e = tk_e[blockIdx.x * 256 + tid];
  atomicAdd(&h[e], 1);
  __syncthreads();
  if (tid < NEXP) blockhist[blockIdx.x * NEXP + tid] = h[tid];
}

// ---------------- scan ----------------
__global__ __launch_bounds__(512)
void k_scan2(const int* __restrict__ blockhist, int* __restrict__ counts,
             int* __restrict__ offsets, int* __restrict__ tp,
             int* __restrict__ blockbase)
{
  __shared__ int ltot[NEXP];
  __shared__ int loff[NEXP + 1];
  int tid = threadIdx.x;
  int lane = tid & 63, e = tid >> 6;
  int o0 = blockhist[lane * NEXP + e];
  int o1 = blockhist[(64 + lane) * NEXP + e];
  int h0 = o0, h1 = o1;
#pragma unroll
  for (int d = 1; d < 64; d <<= 1) { int v = __shfl_up(h0, d); if (lane >= d) h0 += v; }
  int s0 = __shfl(h0, 63);
#pragma unroll
  for (int d = 1; d < 64; d <<= 1) { int v = __shfl_up(h1, d); if (lane >= d) h1 += v; }
  h1 += s0;
  if (lane == 63) ltot[e] = h1;
  __syncthreads();
  if (tid == 0) {
    loff[0] = 0;
    int tpv = 0; tp[0] = 0;
    for (int k = 0; k < NEXP; ++k) {
      loff[k + 1] = loff[k] + ltot[k];
      counts[k] = ltot[k];
      offsets[k] = loff[k];
      tpv += (ltot[k] + 127) / 128;
      tp[k + 1] = tpv;
    }
    offsets[NEXP] = loff[NEXP];
  }
  __syncthreads();
  int base = loff[e];
  blockbase[lane * NEXP + e]        = base + h0 - o0;
  blockbase[(64 + lane) * NEXP + e] = base + h1 - o1;
}

// ---------------- stable slot assign + gather ----------------
__global__ __launch_bounds__(256)
void k_assign_gather(const float* __restrict__ x, const int* __restrict__ tk_e,
                     const float* __restrict__ tk_w,
                     const int* __restrict__ blockbase,
                     int* __restrict__ tok2slot, float* __restrict__ slot_w,
                     unsigned short* __restrict__ Xg)
{
  __shared__ int eh[256];
  __shared__ int sslot[256];
  int b = blockIdx.x, tid = threadIdx.x;
  int pick = b * 256 + tid;
  int e = tk_e[pick];
  eh[tid] = e;
  __syncthreads();
  int rank = 0;
  for (int j = 0; j < tid; ++j) rank += (eh[j] == e);
  int slot = blockbase[b * NEXP + e] + rank;
  sslot[tid] = slot;
  tok2slot[pick] = slot;          // pick = 2*token + kk
  slot_w[slot] = tk_w[pick];
  __syncthreads();
  int lane = tid & 63, wid = tid >> 6;
  for (int p = wid * 64; p < wid * 64 + 64; ++p) {
    int token = (b * 256 + p) >> 1;
    int s = sslot[p];
    const float4* src = (const float4*)(x + (size_t)token * CDIM);
    ushort4* dst = (ushort4*)(Xg + (size_t)s * CDIM);
#pragma unroll
    for (int i = 0; i < 3; ++i) {
      float4 v = src[i * 64 + lane];
      ushort4 hh;
      hh.x = f2bf(v.x); hh.y = f2bf(v.y); hh.z = f2bf(v.z); hh.w = f2bf(v.w);
      dst[i * 64 + lane] = hh;
    }
  }
}

// ---------------- grouped GEMM: 128x128 tile, BK=32, depth-3 pipeline -------
// Tiles [t0, t0+yTiles) of the global tile list. Full-K, single pass.
// EPI==0: A = Xg (global slot rows), epilogue H[(by-t0)*128+row] = bf16(gelu(acc+b1))
// EPI==1: A = H (chunk-local rows), epilogue Yslot[slot] = bf16((acc+b2)*wt)  [contiguous]
template <int EPI>
__device__ __forceinline__ void gemm_body(
    const unsigned short* __restrict__ A, int lda,
    const unsigned short* __restrict__ B, int ldb, long sB,
    int Ksteps,
    const int* __restrict__ counts, const int* __restrict__ offsets,
    const int* __restrict__ tp, int t0,
    const float* __restrict__ bias, int biasStride,
    unsigned short* __restrict__ Hout, int ldh,
    unsigned short* __restrict__ Yout, const float* __restrict__ slot_w,
    int gx, int nwg)
{
  __shared__ __align__(16) char lds[5 * 16384];

  // XCD-aware bijective swizzle (m204)
  int orig = blockIdx.y * gx + blockIdx.x;
  int q = nwg >> 3, r = nwg & 7;
  int xcd = orig & 7, j = orig >> 3;
  int wgid = (xcd < r ? xcd * (q + 1) : r * (q + 1) + (xcd - r) * q) + j;
  int bx = wgid % gx, byl = wgid / gx;
  int by = t0 + byl;

  if (by >= tp[NEXP]) return;
  int e = 0;
  while (by >= tp[e + 1]) ++e;
  int m0 = (by - tp[e]) * 128;
  int cnt = counts[e];
  int rowbase = offsets[e];
  int n0 = bx * 128;

  const unsigned short* Bexp = B + (long)e * sB + (long)n0 * ldb;
  const unsigned short* Aexp =
      (EPI == 0) ? A + (long)(rowbase + m0) * lda
                 : A + (long)(byl * 128) * lda;

  int tid = threadIdx.x;
  int lane = tid & 63, wid = tid >> 6;
  int wm = wid >> 1, wn = wid & 1;
  int ar = lane & 15, kg = lane >> 4;
  int kgs = (kg ^ ((ar >> 1) & 3)) << 4;

  int rA0 = tid >> 2;
  int cA0 = tid & 3;
  int ksw = (cA0 ^ ((rA0 >> 1) & 3)) << 3;
  const unsigned short* As0 = Aexp + (long)rA0 * lda + ksw;
  const unsigned short* As1 = Aexp + (long)(rA0 + 64) * lda + ksw;
  const unsigned short* Bs0 = Bexp + (long)rA0 * ldb + ksw;
  const unsigned short* Bs1 = Bexp + (long)(rA0 + 64) * ldb + ksw;

  f32x4 acc[4][4] = {};

  auto STAGE = [&](int t) {
    char* bb = lds + (t % 5) * 16384;
    int ko = t * 32;
    async16(As0 + ko, bb + wid * 1024);
    async16(As1 + ko, bb + 4096 + wid * 1024);
    async16(Bs0 + ko, bb + 8192 + wid * 1024);
    async16(Bs1 + ko, bb + 12288 + wid * 1024);
  };

  STAGE(0); STAGE(1); STAGE(2);

  for (int ks = 0; ks < Ksteps; ++ks) {
    if (ks + 3 < Ksteps) {
      STAGE(ks + 3);
      asm volatile("s_waitcnt vmcnt(12)" ::: "memory");
    } else if (ks + 2 < Ksteps) {
      asm volatile("s_waitcnt vmcnt(8)" ::: "memory");
    } else if (ks + 1 < Ksteps) {
      asm volatile("s_waitcnt vmcnt(4)" ::: "memory");
    } else {
      asm volatile("s_waitcnt vmcnt(0)" ::: "memory");
    }
    __builtin_amdgcn_s_barrier();
    asm volatile("" ::: "memory");

    const char* bb = lds + (ks % 5) * 16384;
    const char* bA = bb + (wm * 64 + ar) * 64 + kgs;
    const char* bB = bb + 8192 + (wn * 64 + ar) * 64 + kgs;
    bf16x8 af[4], bfr[4];
#pragma unroll
    for (int i = 0; i < 4; ++i) af[i] = *(const bf16x8*)(bA + i * 1024);
#pragma unroll
    for (int i = 0; i < 4; ++i) bfr[i] = *(const bf16x8*)(bB + i * 1024);
#pragma unroll
    for (int mi = 0; mi < 4; ++mi)
#pragma unroll
      for (int ni = 0; ni < 4; ++ni)
        acc[mi][ni] = __builtin_amdgcn_mfma_f32_16x16x32_bf16(af[mi], bfr[ni],
                                                              acc[mi][ni], 0, 0, 0);
  }

  if (EPI == 0) {
#pragma unroll
    for (int ni = 0; ni < 4; ++ni) {
      int ncol = n0 + wn * 64 + ni * 16 + ar;
      float bv = bias[e * biasStride + ncol];
#pragma unroll
      for (int mi = 0; mi < 4; ++mi) {
#pragma unroll
        for (int r = 0; r < 4; ++r) {
          int rowl = wm * 64 + mi * 16 + kg * 4 + r;
          if (m0 + rowl < cnt) {
            float v = acc[mi][ni][r] + bv;
            v = 0.5f * v * (1.0f + erff(v * 0.70710678118654752f));
            Hout[(long)(byl * 128 + rowl) * ldh + ncol] = f2bf(v);
          }
        }
      }
    }
  } else {
#pragma unroll
    for (int mi = 0; mi < 4; ++mi) {
#pragma unroll
      for (int r = 0; r < 4; ++r) {
        int rowl = wm * 64 + mi * 16 + kg * 4 + r;
        if (m0 + rowl < cnt) {
          int slot = rowbase + m0 + rowl;
          float wt = slot_w[slot];
          unsigned short* dst = Yout + (long)slot * CDIM;
#pragma unroll
          for (int ni = 0; ni < 4; ++ni) {
            int ncol = n0 + wn * 64 + ni * 16 + ar;
            float v = (acc[mi][ni][r] + bias[e * biasStride + ncol]) * wt;
            dst[ncol] = f2bf(v);
          }
        }
      }
    }
  }
}

__global__ __launch_bounds__(256)
void k_gemm1(const unsigned short* __restrict__ A, int lda,
             const unsigned short* __restrict__ B, int ldb, long sB,
             int Ksteps, const int* __restrict__ counts,
             const int* __restrict__ offsets, const int* __restrict__ tp,
             int t0, const float* __restrict__ bias, int biasStride,
             unsigned short* __restrict__ Hout, int ldh, int gx, int nwg)
{
  gemm_body<0>(A, lda, B, ldb, sB, Ksteps, counts, offsets, tp, t0,
               bias, biasStride, Hout, ldh, nullptr, nullptr, gx, nwg);
}

__global__ __launch_bounds__(256)
void k_gemm2(const unsigned short* __restrict__ A, int lda,
             const unsigned short* __restrict__ B, int ldb, long sB,
             int Ksteps, const int* __restrict__ counts,
             const int* __restrict__ offsets, const int* __restrict__ tp,
             int t0, const float* __restrict__ bias, int biasStride,
             unsigned short* __restrict__ Yout, const float* __restrict__ slot_w,
             int gx, int nwg)
{
  gemm_body<1>(A, lda, B, ldb, sB, Ksteps, counts, offsets, tp, t0,
               bias, biasStride, nullptr, 0, Yout, slot_w, gx, nwg);
}

// ---------------- final combine: out[t] = Y[slot0] + Y[slot1] ----------------
__global__ __launch_bounds__(256)
void k_combine(const unsigned short* __restrict__ Y,
               const int* __restrict__ tok2slot, float* __restrict__ out)
{
  int t = blockIdx.x * 4 + (threadIdx.x >> 6);
  int lane = threadIdx.x & 63;
  int s0 = tok2slot[2 * t], s1 = tok2slot[2 * t + 1];
  const ushort4* y0 = (const ushort4*)(Y + (size_t)s0 * CDIM);
  const ushort4* y1 = (const ushort4*)(Y + (size_t)s1 * CDIM);
  float4* o = (float4*)(out + (size_t)t * CDIM);
#pragma unroll
  for (int i = 0; i < 3; ++i) {
    ushort4 a = y0[i * 64 + lane];
    ushort4 b = y1[i * 64 + lane];
    float4 r;
    r.x = bf2f(a.x) + bf2f(b.x);
    r.y = bf2f(a.y) + bf2f(b.y);
    r.z = bf2f(a.z) + bf2f(b.z);
    r.w = bf2f(a.w) + bf2f(b.w);
    o[i * 64 + lane] = r;
  }
}

extern "C" void kernel_launch(void* const* d_in, const int* in_sizes, int n_in,
                              void* d_out, int out_size, void* d_ws, size_t ws_size,
                              hipStream_t stream) {
  const float* x        = (const float*)d_in[0];
  const float* router_w = (const float*)d_in[1];
  const float* w1       = (const float*)d_in[2];
  const float* b1       = (const float*)d_in[3];
  const float* w2       = (const float*)d_in[4];
  const float* b2       = (const float*)d_in[5];
  float* out = (float*)d_out;

  char* ws = (char*)d_ws;
  size_t off = 0;
  auto alloc = [&](size_t bytes) -> void* {
    void* p = ws + off;
    off = (off + bytes + 255) & ~(size_t)255;
    return p;
  };
  int*   counts     = (int*)alloc(NEXP * 4);
  int*   offsets    = (int*)alloc((NEXP + 1) * 4);
  int*   tp         = (int*)alloc((NEXP + 1) * 4);
  int*   tk_e       = (int*)alloc((size_t)NSLOT * 4);
  float* tk_w       = (float*)alloc((size_t)NSLOT * 4);
  int*   blockhist  = (int*)alloc((size_t)HBLK * NEXP * 4);
  int*   blockbase  = (int*)alloc((size_t)HBLK * NEXP * 4);
  int*   tok2slot   = (int*)alloc((size_t)NSLOT * 4);
  float* slot_w     = (float*)alloc((size_t)NSLOT * 4);
  unsigned short* Yslot = (unsigned short*)alloc((size_t)NSLOT * CDIM * 2);
  unsigned short* w1t = (unsigned short*)alloc((size_t)NEXP * FDIM * CDIM * 2);
  unsigned short* w2t = (unsigned short*)alloc((size_t)NEXP * CDIM * FDIM * 2);
  unsigned short* Xg  = (unsigned short*)alloc((size_t)(NSLOT + 128) * CDIM * 2);
  // M-chunking: TPC tiles per chunk; H holds TPC*128 rows x FDIM bf16
  int TPC = 132;   // 2 chunks if ws allows, else 66 -> 4 chunks
  if (off + ((size_t)TPC * 128 + 128) * FDIM * 2 > ws_size) TPC = 66;
  unsigned short* H = (unsigned short*)alloc(((size_t)TPC * 128 + 128) * FDIM * 2);

  k_transpose<<<dim3(FDIM / 32, CDIM / 32, NEXP), 256, 0, stream>>>(w1, w1t, CDIM, FDIM);
  k_transpose<<<dim3(CDIM / 32, FDIM / 32, NEXP), 256, 0, stream>>>(w2, w2t, FDIM, CDIM);
  k_router<<<NTOK / 4, 256, 0, stream>>>(x, router_w, tk_e, tk_w);
  k_hist<<<HBLK, 256, 0, stream>>>(tk_e, blockhist);
  k_scan2<<<1, 512, 0, stream>>>(blockhist, counts, offsets, tp, blockbase);
  k_assign_gather<<<HBLK, 256, 0, stream>>>(x, tk_e, tk_w, blockbase,
                                            tok2slot, slot_w, Xg);

  for (int t0 = 0; t0 < MAXTILES; t0 += TPC) {
    int yT = (MAXTILES - t0 < TPC) ? (MAXTILES - t0) : TPC;
    int gx1 = FDIM / 128;   // 24
    k_gemm1<<<dim3(gx1, yT), 256, 0, stream>>>(
        Xg, CDIM, w1t, CDIM, (long)FDIM * CDIM, CDIM / 32,
        counts, offsets, tp, t0, b1, FDIM, H, FDIM, gx1, gx1 * yT);
    int gx2 = CDIM / 128;   // 6
    k_gemm2<<<dim3(gx2, yT), 256, 0, stream>>>(
        H, FDIM, w2t, FDIM, (long)CDIM * FDIM, FDIM / 32,
        counts, offsets, tp, t0, b2, CDIM, Yslot, slot_w, gx2, gx2 * yT);
  }
  k_combine<<<NTOK / 4, 256, 0, stream>>>(Yslot, tok2slot, out);
}